// Round 12
// baseline (42.367 us; speedup 1.0000x reference)
//
#include <hip/hip_runtime.h>
#include <hip/hip_bf16.h>

typedef __attribute__((ext_vector_type(8))) short short8;
typedef __attribute__((ext_vector_type(4))) float f32x4;
typedef __attribute__((ext_vector_type(2))) float f32x2;
typedef __attribute__((ext_vector_type(4))) unsigned int u32x4;

#define NROWS   262144
#define ODIM    64
#define NBLOCKS 256
#define TPB     1024          // 16 waves; 98 KB LDS -> 1 block/CU -> 4 waves/SIMD
#define INV2PI  0.15915494309189535f

__device__ __forceinline__ float cos2pi(float f){ float r; asm("v_cos_f32 %0, %1" : "=v"(r) : "v"(f)); return r; }
__device__ __forceinline__ float sin2pi(float f){ float r; asm("v_sin_f32 %0, %1" : "=v"(r) : "v"(f)); return r; }
// packed dual-fp32 (VOP3P, full-rate: 157.3 TF spec = packed rate)
__device__ __forceinline__ f32x2 pk_mul(f32x2 a, f32x2 b){
    f32x2 d; asm("v_pk_mul_f32 %0, %1, %2" : "=v"(d) : "v"(a), "v"(b)); return d; }
__device__ __forceinline__ f32x2 pk_fma(f32x2 a, f32x2 b, f32x2 c){
    f32x2 d; asm("v_pk_fma_f32 %0, %1, %2, %3" : "=v"(d) : "v"(a), "v"(b), "v"(c)); return d; }
__device__ __forceinline__ f32x2 pk_fms(f32x2 a, f32x2 b, f32x2 c){   // a*b - c
    f32x2 d; asm("v_pk_fma_f32 %0, %1, %2, %3 neg_lo:[0,0,1] neg_hi:[0,0,1]"
                 : "=v"(d) : "v"(a), "v"(b), "v"(c)); return d; }
// D.lo = bf16(lo), D.hi = bf16(hi), RNE — 2 features per instruction
__device__ __forceinline__ unsigned pkbf(float lo, float hi){
    unsigned r; asm("v_cvt_pk_bf16_f32 %0, %1, %2" : "=v"(r) : "v"(lo), "v"(hi)); return r; }
__device__ __forceinline__ short8 as_s8(u32x4 v){ union{u32x4 u; short8 s;} x; x.u = v; return x.s; }
__device__ __forceinline__ short bf16_of(float f){
    union { __hip_bfloat16 h; short s; } u; u.h = __float2bfloat16(f); return u.s; }

// out[b,o] = sum_k F[b,k] W[o,k]; k = br*384 + i*128 + g; harmonic = g+1
// cos k-step kk (0..11) pairs with sin k-step kk+12 (identical harmonics).
extern "C" __global__ void __launch_bounds__(TPB, 4)
fourier_mfma(const float* __restrict__ x,
             const float* __restrict__ coeffs,
             const float* __restrict__ bias,
             float* __restrict__ out)
{
    // Fragment-ordered bf16 weights: [ks][nt][lane] -> 8 bf16 (one ds_read_b128)
    __shared__ short8 Wlds[24 * 4 * 64];   // 98304 B

    const int tid = threadIdx.x;

    // ---- one-time weight staging: fp32 global -> bf16 fragments in LDS ----
    for (int fl = tid; fl < 24*4*64; fl += TPB) {
        const int ks = fl >> 8;
        const int nt = (fl >> 6) & 3;
        const int ln = fl & 63;
        const int o  = nt*16 + (ln & 15);   // B-frag: col = lane & 15
        const int kg = ln >> 4;             // k sub-band = 4*(lane>>4)
        union { short8 v; short s[8]; } fr;
        #pragma unroll
        for (int h = 0; h < 2; ++h) {
            const int kb  = ks*32 + h*16;
            const int br  = (kb >= 384) ? 1 : 0;
            const int rem = kb - br*384;
            const int ii  = rem >> 7;
            const int g0  = (rem & 127) + kg*4;
            const float* wp = coeffs + (((br*ODIM + o)*3 + ii) << 7) + g0;
            #pragma unroll
            for (int j = 0; j < 4; ++j) fr.s[h*4 + j] = bf16_of(wp[j]);
        }
        Wlds[fl] = fr.v;
    }
    __syncthreads();

    const int lane = tid & 63;
    const int wid  = tid >> 6;
    const int mrow = lane & 15;     // A-frag row within 16-row tile
    const int kgrp = lane >> 4;     // k sub-band / D-row group
    const float hs = (float)(4*kgrp + 1);   // lane's starting harmonic per 16-block

    float bcol[4];
    #pragma unroll
    for (int nt = 0; nt < 4; ++nt) bcol[nt] = bias[nt*16 + mrow];

    const int unit = blockIdx.x * 16 + wid;   // 256*16 = 4096 units = NROWS/64
    const int base = unit * 64;

    // Two sequential 32-row passes; each pass handles a packed row-pair (rr=0,1).
    #pragma unroll 1
    for (int rg = 0; rg < 2; ++rg) {
        const int rowA = base + (rg*2 + 0)*16 + mrow;
        const int rowB = base + (rg*2 + 1)*16 + mrow;

        f32x2 xr[3];
        #pragma unroll
        for (int i = 0; i < 3; ++i)
            xr[i] = (f32x2){ x[rowA*3 + i] * INV2PI, x[rowB*3 + i] * INV2PI };

        f32x4 acc[2][4];
        #pragma unroll
        for (int rr = 0; rr < 2; ++rr)
            #pragma unroll
            for (int nt = 0; nt < 4; ++nt)
                acc[rr][nt] = (f32x4){0.f, 0.f, 0.f, 0.f};

        f32x2 cvp, svp, c16p, s16p, stc, sts;

        #pragma unroll 1
        for (int kk = 0; kk < 12; ++kk) {          // cos k-step; sin is kk+12
            // early-issue this step's 8 b-frags (latency hides under feature gen)
            short8 bfr[8];                          // [branch*4 + nt], static idx
            #pragma unroll
            for (int nt = 0; nt < 4; ++nt) {
                bfr[nt]     = Wlds[(kk*4 + nt)*64 + lane];
                bfr[4 + nt] = Wlds[((kk + 12)*4 + nt)*64 + lane];
            }

            if ((kk & 3) == 0) {                    // uniform branch, every 4th iter
                const int i = kk >> 2;
                const f32x2 a = xr[i];
                cvp = (f32x2){ cos2pi(a.x), cos2pi(a.y) };   // rotate by 1*x
                svp = (f32x2){ sin2pi(a.x), sin2pi(a.y) };
                f32x2 t = (f32x2){ 16.f*a.x, 16.f*a.y };
                t.x -= floorf(t.x); t.y -= floorf(t.y);
                c16p = (f32x2){ cos2pi(t.x), cos2pi(t.y) };  // rotate by 16*x
                s16p = (f32x2){ sin2pi(t.x), sin2pi(t.y) };
                f32x2 u = (f32x2){ hs*a.x, hs*a.y };
                u.x -= floorf(u.x); u.y -= floorf(u.y);
                stc = (f32x2){ cos2pi(u.x), cos2pi(u.y) };   // state: harmonic 4*kgrp+1
                sts = (f32x2){ sin2pi(u.x), sin2pi(u.y) };
            }

            // Packed feature gen: ~60 VALU/kk (vs ~136 scalarized)
            u32x4 FCA, FCB, FSA, FSB;
            {
                // h = 0
                f32x2 c0 = stc, s0 = sts;
                f32x2 c1 = pk_fms(c0, cvp, pk_mul(s0, svp));
                f32x2 s1 = pk_fma(s0, cvp, pk_mul(c0, svp));
                FCA.x = pkbf(c0.x, c1.x);  FCB.x = pkbf(c0.y, c1.y);
                FSA.x = pkbf(s0.x, s1.x);  FSB.x = pkbf(s0.y, s1.y);
                f32x2 c2 = pk_fms(c1, cvp, pk_mul(s1, svp));
                f32x2 s2 = pk_fma(s1, cvp, pk_mul(c1, svp));
                f32x2 c3 = pk_fms(c2, cvp, pk_mul(s2, svp));
                f32x2 s3 = pk_fma(s2, cvp, pk_mul(c2, svp));
                FCA.y = pkbf(c2.x, c3.x);  FCB.y = pkbf(c2.y, c3.y);
                FSA.y = pkbf(s2.x, s3.x);  FSB.y = pkbf(s2.y, s3.y);
                f32x2 nc = pk_fms(stc, c16p, pk_mul(sts, s16p));
                f32x2 ns = pk_fma(sts, c16p, pk_mul(stc, s16p));
                stc = nc; sts = ns;
                // h = 1
                c0 = stc; s0 = sts;
                c1 = pk_fms(c0, cvp, pk_mul(s0, svp));
                s1 = pk_fma(s0, cvp, pk_mul(c0, svp));
                FCA.z = pkbf(c0.x, c1.x);  FCB.z = pkbf(c0.y, c1.y);
                FSA.z = pkbf(s0.x, s1.x);  FSB.z = pkbf(s0.y, s1.y);
                c2 = pk_fms(c1, cvp, pk_mul(s1, svp));
                s2 = pk_fma(s1, cvp, pk_mul(c1, svp));
                c3 = pk_fms(c2, cvp, pk_mul(s2, svp));
                s3 = pk_fma(s2, cvp, pk_mul(c2, svp));
                FCA.w = pkbf(c2.x, c3.x);  FCB.w = pkbf(c2.y, c3.y);
                FSA.w = pkbf(s2.x, s3.x);  FSB.w = pkbf(s2.y, s3.y);
                nc = pk_fms(stc, c16p, pk_mul(sts, s16p));
                ns = pk_fma(sts, c16p, pk_mul(stc, s16p));
                stc = nc; sts = ns;
            }

            const short8 fAc = as_s8(FCA);
            const short8 fBc = as_s8(FCB);
            const short8 fAs = as_s8(FSA);
            const short8 fBs = as_s8(FSB);

            // MFMAs grouped by A-frag: same-acc reuse distance = 8
            #pragma unroll
            for (int nt = 0; nt < 4; ++nt)
                acc[0][nt] = __builtin_amdgcn_mfma_f32_16x16x32_bf16(fAc, bfr[nt], acc[0][nt], 0, 0, 0);
            #pragma unroll
            for (int nt = 0; nt < 4; ++nt)
                acc[1][nt] = __builtin_amdgcn_mfma_f32_16x16x32_bf16(fBc, bfr[nt], acc[1][nt], 0, 0, 0);
            #pragma unroll
            for (int nt = 0; nt < 4; ++nt)
                acc[0][nt] = __builtin_amdgcn_mfma_f32_16x16x32_bf16(fAs, bfr[4+nt], acc[0][nt], 0, 0, 0);
            #pragma unroll
            for (int nt = 0; nt < 4; ++nt)
                acc[1][nt] = __builtin_amdgcn_mfma_f32_16x16x32_bf16(fBs, bfr[4+nt], acc[1][nt], 0, 0, 0);
        }

        // Epilogue. D layout: col = lane&15, row = 4*(lane>>4) + reg  [m89-verified]
        #pragma unroll
        for (int rr = 0; rr < 2; ++rr) {
            const int row0 = base + (rg*2 + rr)*16 + kgrp*4;
            #pragma unroll
            for (int nt = 0; nt < 4; ++nt) {
                #pragma unroll
                for (int q = 0; q < 4; ++q) {
                    out[(row0 + q)*ODIM + nt*16 + mrow] = acc[rr][nt][q] + bcol[nt];
                }
            }
        }
    }
}

extern "C" void kernel_launch(void* const* d_in, const int* in_sizes, int n_in,
                              void* d_out, int out_size, void* d_ws, size_t ws_size,
                              hipStream_t stream) {
    const float* x      = (const float*)d_in[0];
    const float* coeffs = (const float*)d_in[1];
    const float* bias   = (const float*)d_in[2];
    float* out = (float*)d_out;
    (void)in_sizes; (void)n_in; (void)out_size; (void)d_ws; (void)ws_size;
    hipLaunchKernelGGL(fourier_mfma, dim3(NBLOCKS), dim3(TPB), 0, stream, x, coeffs, bias, out);
}